// Round 1
// baseline (19389.236 us; speedup 1.0000x reference)
//
#include <hip/hip_runtime.h>
#include <math.h>

#define NN   4096
#define EE   65536
#define HID  768
#define SEQ  512
#define NHD  12
#define HDM  64
#define FFD  3072

// ---------- helpers ----------
__device__ __forceinline__ unsigned fenc(float f){
    unsigned u = __float_as_uint(f);
    return (u & 0x80000000u) ? ~u : (u | 0x80000000u);
}
__device__ __forceinline__ float fdec(unsigned e){
    unsigned u = (e & 0x80000000u) ? (e & 0x7FFFFFFFu) : ~e;
    return __uint_as_float(u);
}
__device__ __forceinline__ float gelu_exact(float x){
    return 0.5f * x * (1.0f + erff(x * 0.7071067811865476f));
}

// ---------- utility kernels ----------
__global__ void zero_f(float* p, int n){
    int i = blockIdx.x*256 + threadIdx.x;
    if (i < n) p[i] = 0.0f;
}
__global__ void zero_i(int* p, int n){
    int i = blockIdx.x*256 + threadIdx.x;
    if (i < n) p[i] = 0;
}
__global__ void copy_i(const int* s, int* d, int n){
    int i = blockIdx.x*256 + threadIdx.x;
    if (i < n) d[i] = s[i];
}

// ---------- generic fp32 GEMM: C = act(A@B + bias) ----------
// A: MxK row-major (lda), B: KxN row-major (ldb), C: MxN row-major (ldc)
// Requires M%128==0, K%16==0, N%4==0. N tail handled by guards.
template<int ACT>   // 0 none, 1 relu, 2 gelu
__global__ __launch_bounds__(256) void gemm_k(
    const float* __restrict__ A, const float* __restrict__ B,
    const float* __restrict__ bias, float* __restrict__ C,
    int M, int N, int K, int lda, int ldb, int ldc)
{
    __shared__ float As[16][132];
    __shared__ float Bs[16][132];
    const int bm = blockIdx.y * 128, bn = blockIdx.x * 128;
    const int t  = threadIdx.x;
    const int tx = t & 15, ty = t >> 4;
    const int arow = t >> 2,  ac4 = (t & 3) << 2;
    const int brow = t >> 5,  bc4 = (t & 31) << 2;
    const bool bok = (bn + bc4) < N;

    float acc[8][8] = {};
    const float* Ap  = A + (long)(bm + arow) * lda + ac4;
    const float* Ap2 = Ap + 64L * lda;
    const float* Bp  = B + (long)brow * ldb + bn + bc4;

    for (int k0 = 0; k0 < K; k0 += 16){
        float4 a0 = *(const float4*)(Ap  + k0);
        float4 a1 = *(const float4*)(Ap2 + k0);
        float4 b0 = make_float4(0,0,0,0), b1 = make_float4(0,0,0,0);
        if (bok){
            b0 = *(const float4*)(Bp + (long)k0 * ldb);
            b1 = *(const float4*)(Bp + (long)(k0 + 8) * ldb);
        }
        As[ac4+0][arow] = a0.x; As[ac4+1][arow] = a0.y;
        As[ac4+2][arow] = a0.z; As[ac4+3][arow] = a0.w;
        As[ac4+0][arow+64] = a1.x; As[ac4+1][arow+64] = a1.y;
        As[ac4+2][arow+64] = a1.z; As[ac4+3][arow+64] = a1.w;
        *(float4*)&Bs[brow  ][bc4] = b0;
        *(float4*)&Bs[brow+8][bc4] = b1;
        __syncthreads();
        #pragma unroll
        for (int k = 0; k < 16; k++){
            float4 t0 = *(const float4*)&As[k][ty<<2];
            float4 t1 = *(const float4*)&As[k][64 + (ty<<2)];
            float4 u0 = *(const float4*)&Bs[k][tx<<2];
            float4 u1 = *(const float4*)&Bs[k][64 + (tx<<2)];
            float a_[8] = {t0.x,t0.y,t0.z,t0.w,t1.x,t1.y,t1.z,t1.w};
            float b_[8] = {u0.x,u0.y,u0.z,u0.w,u1.x,u1.y,u1.z,u1.w};
            #pragma unroll
            for (int i = 0; i < 8; i++)
                #pragma unroll
                for (int j = 0; j < 8; j++)
                    acc[i][j] += a_[i] * b_[j];
        }
        __syncthreads();
    }

    #pragma unroll
    for (int i = 0; i < 8; i++){
        int row = bm + ((i < 4) ? ((ty<<2) + i) : (64 + (ty<<2) + i - 4));
        #pragma unroll
        for (int jh = 0; jh < 2; jh++){
            int col = bn + jh*64 + (tx<<2);
            if (col < N){
                float o[4];
                #pragma unroll
                for (int c = 0; c < 4; c++){
                    float v = acc[i][jh*4 + c] + (bias ? bias[col + c] : 0.0f);
                    if (ACT == 1) v = fmaxf(v, 0.0f);
                    if (ACT == 2) v = gelu_exact(v);
                    o[c] = v;
                }
                *(float4*)(C + (long)row * ldc + col) = make_float4(o[0],o[1],o[2],o[3]);
            }
        }
    }
}

// ---------- spatial embedding gather: feat[:,384:768] ----------
__global__ void spat_k(const int* __restrict__ bbox, const float* __restrict__ Ex,
                       const float* __restrict__ Ey, float* __restrict__ feat)
{
    int idx = blockIdx.x*256 + threadIdx.x;
    if (idx >= NN*384) return;
    int n = idx / 384, j = idx % 384;
    int q = j / 96, jj = j % 96;
    const float* tab = (q == 0 || q == 2) ? Ex : Ey;
    int bi = bbox[n*4 + q];
    feat[(long)n*1536 + 384 + j] = tab[bi*96 + jj];
}

// ---------- CSR build ----------
__global__ void count_k(const int* __restrict__ dst, const float* __restrict__ ea,
                        int* __restrict__ cnt, float* __restrict__ sumea)
{
    int e = blockIdx.x*256 + threadIdx.x;
    if (e >= EE) return;
    int d = dst[e];
    atomicAdd(&cnt[d], 1);
    atomicAdd(&sumea[d], ea[e]);
}
__global__ __launch_bounds__(256) void scan_k(const int* __restrict__ cnt, int* __restrict__ offs)
{
    __shared__ int part[256];
    int t = threadIdx.x;
    int base = t*16;
    int loc[16]; int s = 0;
    #pragma unroll
    for (int i = 0; i < 16; i++){ loc[i] = s; s += cnt[base + i]; }
    part[t] = s;
    __syncthreads();
    for (int off = 1; off < 256; off <<= 1){
        int v = (t >= off) ? part[t - off] : 0;
        __syncthreads();
        part[t] += v;
        __syncthreads();
    }
    int pre = (t == 0) ? 0 : part[t-1];
    #pragma unroll
    for (int i = 0; i < 16; i++) offs[base + i] = pre + loc[i];
    if (t == 255) offs[NN] = part[255];
}
__global__ void loopea_k(const int* __restrict__ cnt, float* __restrict__ sumea)
{
    int i = blockIdx.x*256 + threadIdx.x;
    if (i < NN) sumea[i] = sumea[i] / fmaxf((float)cnt[i], 1.0f);
}
__global__ void fill_k(const int* __restrict__ dst, int* __restrict__ pos, int* __restrict__ eid)
{
    int e = blockIdx.x*256 + threadIdx.x;
    if (e >= EE) return;
    int d = dst[e];
    int idx = atomicAdd(&pos[d], 1);
    eid[idx] = e;
}

// ---------- GAT per-node attention coefficients ----------
__global__ __launch_bounds__(64) void headprep_k(
    const float* __restrict__ h, const float* __restrict__ as_,
    const float* __restrict__ ad_, float* __restrict__ asrc, float* __restrict__ adst)
{
    int n = blockIdx.x, lane = threadIdx.x;
    int c0 = lane * 12;
    float s = 0.f, d = 0.f;
    #pragma unroll
    for (int i = 0; i < 12; i++){
        float hv = h[(long)n*HID + c0 + i];
        s += hv * as_[c0 + i];
        d += hv * ad_[c0 + i];
    }
    #pragma unroll
    for (int o = 1; o < 8; o <<= 1){
        s += __shfl_xor(s, o, 64);
        d += __shfl_xor(d, o, 64);
    }
    if ((lane & 7) == 0){
        int gh = lane >> 3;
        asrc[n*8 + gh] = s;
        adst[n*8 + gh] = d;
    }
}

// ---------- GAT aggregation (one block per destination node) ----------
__global__ __launch_bounds__(256) void gatagg_k(
    const float* __restrict__ h, const float* __restrict__ asrc, const float* __restrict__ adst,
    const int* __restrict__ src, const float* __restrict__ ea, const float* __restrict__ loopea,
    const int* __restrict__ offs, const int* __restrict__ eid,
    const float* __restrict__ We, const float* __restrict__ ae,
    const float* __restrict__ bias, float* __restrict__ outg)
{
    int n = blockIdx.x, t = threadIdx.x;
    __shared__ float Sh[8], adn[8], alself[8], exself[8], den[8];
    __shared__ unsigned me[8];
    __shared__ float exs[32][8];
    __shared__ int   srcs[32];

    if (t < 8){
        float s = 0.f;
        for (int cc = 0; cc < 96; cc++) s += We[t*96 + cc] * ae[t*96 + cc];
        Sh[t] = s;
        adn[t] = adst[n*8 + t];
        float al = asrc[n*8 + t] + adn[t] + loopea[n] * s;
        al = (al > 0.f) ? al : 0.2f * al;
        alself[t] = al;
        me[t] = fenc(al);
        den[t] = 0.f;
    }
    __syncthreads();
    int e0 = offs[n], deg = offs[n+1] - e0;
    // phase A: per-head max over incoming edges
    for (int idx = t; idx < deg*8; idx += 256){
        int ei_ = idx >> 3, gh = idx & 7;
        int e = eid[e0 + ei_];
        int sn = src[e];
        float al = asrc[sn*8 + gh] + adn[gh] + ea[e]*Sh[gh];
        al = (al > 0.f) ? al : 0.2f * al;
        atomicMax(&me[gh], fenc(al));
    }
    __syncthreads();
    if (t < 8){
        float es = expf(alself[t] - fdec(me[t]));
        exself[t] = es;
        den[t] = es;
    }
    __syncthreads();

    int cs[3], ghc[3];
    float acc[3];
    #pragma unroll
    for (int i = 0; i < 3; i++){
        cs[i] = t + i*256;
        ghc[i] = cs[i] / 96;
        acc[i] = exself[ghc[i]] * h[(long)n*HID + cs[i]];
    }
    const int mygh = t >> 5, le = t & 31;
    const float m_my = fdec(me[mygh]);
    float den_local = 0.f;

    for (int c0 = 0; c0 < deg; c0 += 32){
        int cnt = min(32, deg - c0);
        float ex = 0.f;
        if (le < cnt){
            int e = eid[e0 + c0 + le];
            int sn = src[e];
            if (mygh == 0) srcs[le] = sn;
            float al = asrc[sn*8 + mygh] + adn[mygh] + ea[e]*Sh[mygh];
            al = (al > 0.f) ? al : 0.2f * al;
            ex = expf(al - m_my);
            den_local += ex;
        }
        exs[le][mygh] = ex;
        __syncthreads();
        for (int j = 0; j < cnt; j++){
            const float* hp = h + (long)srcs[j]*HID;
            #pragma unroll
            for (int i = 0; i < 3; i++) acc[i] += exs[j][ghc[i]] * hp[cs[i]];
        }
        __syncthreads();
    }
    atomicAdd(&den[mygh], den_local);
    __syncthreads();
    #pragma unroll
    for (int i = 0; i < 3; i++){
        float o = acc[i] / (den[ghc[i]] + 1e-16f) + bias[cs[i]];
        outg[(long)n*HID + cs[i]] += o;
    }
}

// ---------- LayerNorm (optionally + residual / + pos&type emb / relu-first) ----------
__global__ __launch_bounds__(256) void ln_k(
    const float* __restrict__ in1, const float* __restrict__ in2,
    const float* __restrict__ pos, const float* __restrict__ typ,
    const float* __restrict__ g, const float* __restrict__ be,
    float* __restrict__ out, int ldo, float eps, int dorelu)
{
    int row = blockIdx.x, t = threadIdx.x;
    float v[3];
    #pragma unroll
    for (int i = 0; i < 3; i++){
        int c = t + i*256;
        float x = in1[(long)row*HID + c];
        if (in2) x += in2[(long)row*HID + c];
        if (pos) x += pos[(row & (SEQ-1))*HID + c] + typ[c];
        if (dorelu) x = fmaxf(x, 0.0f);
        v[i] = x;
    }
    float s1 = v[0] + v[1] + v[2];
    float s2 = v[0]*v[0] + v[1]*v[1] + v[2]*v[2];
    #pragma unroll
    for (int o = 32; o > 0; o >>= 1){
        s1 += __shfl_down(s1, o, 64);
        s2 += __shfl_down(s2, o, 64);
    }
    __shared__ float red[8];
    int wid = t >> 6, lane = t & 63;
    if (lane == 0){ red[wid] = s1; red[4 + wid] = s2; }
    __syncthreads();
    if (t == 0){
        red[0] = red[0]+red[1]+red[2]+red[3];
        red[4] = red[4]+red[5]+red[6]+red[7];
    }
    __syncthreads();
    float mu  = red[0] * (1.0f/768.0f);
    float var = fmaxf(red[4] * (1.0f/768.0f) - mu*mu, 0.0f);
    float r = rsqrtf(var + eps);
    #pragma unroll
    for (int i = 0; i < 3; i++){
        int c = t + i*256;
        out[(long)row*ldo + c] = (v[i] - mu)*r*g[c] + be[c];
    }
}

// ---------- attention: one block per (b, head, 32-query tile) ----------
__global__ __launch_bounds__(256) void attn_k(
    const float* __restrict__ Qb, const float* __restrict__ Kb,
    const float* __restrict__ Vb, float* __restrict__ Ob)
{
    const int q0 = blockIdx.x * 32;
    const int hh = blockIdx.y;
    const int b  = blockIdx.z;
    __shared__ float qs[32][HDM];
    __shared__ float kv[64][HDM + 4];
    __shared__ float sc[32][SEQ];
    const int t = threadIdx.x;
    const long basek = (long)b*SEQ*HID + hh*HDM;

    { // load Q tile
        int r = t >> 3, d0 = (t & 7) * 8;
        const float* s = Qb + basek + (long)(q0 + r)*HID + d0;
        *(float4*)&qs[r][d0]     = *(const float4*)s;
        *(float4*)&qs[r][d0 + 4] = *(const float4*)(s + 4);
    }
    __syncthreads();
    const int q = t >> 3, kk0 = t & 7;
    for (int kc = 0; kc < SEQ; kc += 64){
        { // load K chunk
            int r = t >> 2, d0 = (t & 3) * 16;
            const float* s = Kb + basek + (long)(kc + r)*HID + d0;
            *(float4*)&kv[r][d0]      = *(const float4*)s;
            *(float4*)&kv[r][d0 + 4]  = *(const float4*)(s + 4);
            *(float4*)&kv[r][d0 + 8]  = *(const float4*)(s + 8);
            *(float4*)&kv[r][d0 + 12] = *(const float4*)(s + 12);
        }
        __syncthreads();
        for (int kk = kk0; kk < 64; kk += 8){
            float acc = 0.f;
            #pragma unroll
            for (int d4 = 0; d4 < HDM; d4 += 4){
                float4 qv = *(const float4*)&qs[q][d4];
                float4 kvv = *(const float4*)&kv[kk][d4];
                acc += qv.x*kvv.x + qv.y*kvv.y + qv.z*kvv.z + qv.w*kvv.w;
            }
            sc[q][kc + kk] = acc * 0.125f;
        }
        __syncthreads();
    }
    { // softmax rows (8 threads per row)
        int r = t >> 3, sub = t & 7;
        float m = -1e30f;
        for (int j = sub; j < SEQ; j += 8) m = fmaxf(m, sc[r][j]);
        #pragma unroll
        for (int o = 1; o < 8; o <<= 1) m = fmaxf(m, __shfl_xor(m, o, 64));
        float s = 0.f;
        for (int j = sub; j < SEQ; j += 8){
            float p = expf(sc[r][j] - m);
            sc[r][j] = p; s += p;
        }
        #pragma unroll
        for (int o = 1; o < 8; o <<= 1) s += __shfl_xor(s, o, 64);
        float inv = 1.0f / s;
        for (int j = sub; j < SEQ; j += 8) sc[r][j] *= inv;
    }
    __syncthreads();
    // ctx = P @ V
    float acc[8] = {0,0,0,0,0,0,0,0};
    const int d0 = (t & 7) * 8;
    for (int kc = 0; kc < SEQ; kc += 64){
        { // load V chunk
            int r = t >> 2, dd = (t & 3) * 16;
            const float* s = Vb + basek + (long)(kc + r)*HID + dd;
            *(float4*)&kv[r][dd]      = *(const float4*)s;
            *(float4*)&kv[r][dd + 4]  = *(const float4*)(s + 4);
            *(float4*)&kv[r][dd + 8]  = *(const float4*)(s + 8);
            *(float4*)&kv[r][dd + 12] = *(const float4*)(s + 12);
        }
        __syncthreads();
        for (int j = 0; j < 64; j++){
            float p = sc[q][kc + j];
            float4 v0 = *(const float4*)&kv[j][d0];
            float4 v1 = *(const float4*)&kv[j][d0 + 4];
            acc[0] += p*v0.x; acc[1] += p*v0.y; acc[2] += p*v0.z; acc[3] += p*v0.w;
            acc[4] += p*v1.x; acc[5] += p*v1.y; acc[6] += p*v1.z; acc[7] += p*v1.w;
        }
        __syncthreads();
    }
    float* op = Ob + basek + (long)(q0 + q)*HID + d0;
    *(float4*)op       = make_float4(acc[0], acc[1], acc[2], acc[3]);
    *(float4*)(op + 4) = make_float4(acc[4], acc[5], acc[6], acc[7]);
}

// ---------- final projection 768 -> 5 ----------
__global__ void outproj_k(const float* __restrict__ h, const float* __restrict__ W,
                          const float* __restrict__ b, float* __restrict__ out)
{
    int idx = blockIdx.x*256 + threadIdx.x;
    if (idx >= NN*5) return;
    int n = idx / 5, o = idx % 5;
    float acc = b[o];
    for (int k = 0; k < HID; k++) acc += h[(long)n*HID + k] * W[k*5 + o];
    out[idx] = acc;
}

// ---------- host launch ----------
extern "C" void kernel_launch(void* const* d_in, const int* in_sizes, int n_in,
                              void* d_out, int out_size, void* d_ws, size_t ws_size,
                              hipStream_t stream)
{
    const float* text_x = (const float*)d_in[0];
    const float* img_x  = (const float*)d_in[1];
    const int*   bbox   = (const int*)d_in[2];
    const int*   ei[3]  = {(const int*)d_in[3], (const int*)d_in[4], (const int*)d_in[5]};
    const float* ea[3]  = {(const float*)d_in[6], (const float*)d_in[7], (const float*)d_in[8]};
    const float* Wt = (const float*)d_in[9];   const float* bt = (const float*)d_in[10];
    const float* Wi = (const float*)d_in[11];  const float* bi = (const float*)d_in[12];
    const float* Ex = (const float*)d_in[13];  const float* Ey = (const float*)d_in[14];
    const float* Wc = (const float*)d_in[15];  const float* bc = (const float*)d_in[16];
    const float* gat_W  = (const float*)d_in[17];
    const float* gat_as = (const float*)d_in[18];
    const float* gat_ad = (const float*)d_in[19];
    const float* gat_We = (const float*)d_in[20];
    const float* gat_ae = (const float*)d_in[21];
    const float* gat_bias = (const float*)d_in[22];
    const float* ln_g = (const float*)d_in[23]; const float* ln_b = (const float*)d_in[24];
    const float* Wcomb = (const float*)d_in[25]; const float* bcomb = (const float*)d_in[26];
    const float* pos_emb = (const float*)d_in[27]; const float* type_emb = (const float*)d_in[28];
    const float* emb_g = (const float*)d_in[29]; const float* emb_b = (const float*)d_in[30];
    const float* Wq = (const float*)d_in[31]; const float* Wk = (const float*)d_in[32];
    const float* Wv = (const float*)d_in[33]; const float* Wo = (const float*)d_in[34];
    const float* W1 = (const float*)d_in[35]; const float* W2 = (const float*)d_in[36];
    const float* bq = (const float*)d_in[37]; const float* bk = (const float*)d_in[38];
    const float* bv = (const float*)d_in[39]; const float* bo = (const float*)d_in[40];
    const float* bff1 = (const float*)d_in[41]; const float* bff2 = (const float*)d_in[42];
    const float* ln1_g = (const float*)d_in[43]; const float* ln1_b = (const float*)d_in[44];
    const float* ln2_g = (const float*)d_in[45]; const float* ln2_b = (const float*)d_in[46];
    const float* Wout = (const float*)d_in[47]; const float* bout = (const float*)d_in[48];
    float* outp = (float*)d_out;

    // ---- workspace layout ----
    float* feat = (float*)d_ws;                // 4096 x 1536
    float* xb   = feat + (long)NN*1536;        // 4096 x 768
    float* hbuf = xb   + (long)NN*HID;         // 4096 x 768
    float* outg = hbuf + (long)NN*HID;         // 4096 x 768
    float* hb   = outg + (long)NN*HID;         // 4096 x 768
    float* ffb  = hb   + (long)NN*HID;         // 4096 x 3072
    float* asrc = ffb  + (long)NN*FFD;         // 4096 x 8
    float* adst = asrc + NN*8;                 // 4096 x 8
    float* sumea= adst + NN*8;                 // 3 x 4096  (-> loop_ea in place)
    int*   cnt  = (int*)(sumea + 3*NN);        // 3 x 4096
    int*   offs = cnt  + 3*NN;                 // 3 x 4097
    int*   pos  = offs + 3*(NN+1);             // 4096
    int*   eid  = pos  + NN;                   // 3 x 65536
    // BERT-phase aliases (GAT scratch is dead by then)
    float* qb  = hbuf;
    float* kb  = outg;
    float* vb  = xb;
    float* ctx = feat;
    float* tmp = feat + (long)NN*HID;

    // ---- 1. input projections ----
    gemm_k<0><<<dim3(2,32), 256, 0, stream>>>(text_x, Wt, bt, feat,       NN, 192, 768, 768, 192, 1536);
    gemm_k<0><<<dim3(2,32), 256, 0, stream>>>(img_x,  Wi, bi, feat + 192, NN, 192, 512, 512, 192, 1536);
    spat_k<<<(NN*384 + 255)/256, 256, 0, stream>>>(bbox, Ex, Ey, feat);
    // x0 = relu([tp|ip|sp] @ Wc + bc)
    gemm_k<1><<<dim3(6,32), 256, 0, stream>>>(feat, Wc, bc, xb, NN, 768, 768, 1536, 768, 768);

    // ---- 2. CSR per edge type (layer-invariant) ----
    zero_i<<<(3*NN + 255)/256, 256, 0, stream>>>(cnt, 3*NN);
    zero_f<<<(3*NN + 255)/256, 256, 0, stream>>>(sumea, 3*NN);
    for (int t = 0; t < 3; t++){
        count_k<<<EE/256, 256, 0, stream>>>(ei[t] + EE, ea[t], cnt + t*NN, sumea + t*NN);
        scan_k<<<1, 256, 0, stream>>>(cnt + t*NN, offs + t*(NN+1));
        loopea_k<<<NN/256, 256, 0, stream>>>(cnt + t*NN, sumea + t*NN);
        copy_i<<<NN/256, 256, 0, stream>>>(offs + t*(NN+1), pos, NN);
        fill_k<<<EE/256, 256, 0, stream>>>(ei[t] + EE, pos, eid + t*EE);
    }

    // ---- 3. GAT layers ----
    for (int l = 0; l < 2; l++){
        zero_f<<<(NN*HID + 255)/256, 256, 0, stream>>>(outg, NN*HID);
        for (int t = 0; t < 3; t++){
            int lt = l*3 + t;
            gemm_k<0><<<dim3(6,32), 256, 0, stream>>>(xb, gat_W + (long)lt*HID*HID, nullptr, hbuf,
                                                      NN, 768, 768, 768, 768, 768);
            headprep_k<<<NN, 64, 0, stream>>>(hbuf, gat_as + lt*HID, gat_ad + lt*HID, asrc, adst);
            gatagg_k<<<NN, 256, 0, stream>>>(hbuf, asrc, adst, ei[t], ea[t], sumea + t*NN,
                                             offs + t*(NN+1), eid + t*EE,
                                             gat_We + lt*HID, gat_ae + lt*HID,
                                             gat_bias + lt*HID, outg);
        }
        if (l == 0)
            ln_k<<<NN, 256, 0, stream>>>(outg, nullptr, nullptr, nullptr, ln_g, ln_b, xb, 768, 1e-5f, 1);
        else
            ln_k<<<NN, 256, 0, stream>>>(outg, nullptr, nullptr, nullptr, ln_g + HID, ln_b + HID,
                                         feat + 768, 1536, 1e-5f, 1);
    }

    // ---- 4. comb + embedding LN ----
    gemm_k<1><<<dim3(6,32), 256, 0, stream>>>(feat, Wcomb, bcomb, hb, NN, 768, 1536, 1536, 768, 768);
    ln_k<<<NN, 256, 0, stream>>>(hb, nullptr, pos_emb, type_emb, emb_g, emb_b, hb, 768, 1e-12f, 0);

    // ---- 5. BERT layers ----
    for (int l = 0; l < 12; l++){
        long wo_ = (long)l*HID*HID;
        gemm_k<0><<<dim3(6,32), 256, 0, stream>>>(hb, Wq + wo_, bq + l*HID, qb, NN, 768, 768, 768, 768, 768);
        gemm_k<0><<<dim3(6,32), 256, 0, stream>>>(hb, Wk + wo_, bk + l*HID, kb, NN, 768, 768, 768, 768, 768);
        gemm_k<0><<<dim3(6,32), 256, 0, stream>>>(hb, Wv + wo_, bv + l*HID, vb, NN, 768, 768, 768, 768, 768);
        attn_k<<<dim3(16, NHD, 8), 256, 0, stream>>>(qb, kb, vb, ctx);
        gemm_k<0><<<dim3(6,32), 256, 0, stream>>>(ctx, Wo + wo_, bo + l*HID, tmp, NN, 768, 768, 768, 768, 768);
        ln_k<<<NN, 256, 0, stream>>>(hb, tmp, nullptr, nullptr, ln1_g + l*HID, ln1_b + l*HID, hb, 768, 1e-12f, 0);
        gemm_k<2><<<dim3(24,32), 256, 0, stream>>>(hb, W1 + (long)l*HID*FFD, bff1 + l*FFD, ffb,
                                                   NN, 3072, 768, 768, 3072, 3072);
        gemm_k<0><<<dim3(6,32), 256, 0, stream>>>(ffb, W2 + (long)l*FFD*HID, bff2 + l*HID, tmp,
                                                  NN, 768, 3072, 3072, 768, 768);
        ln_k<<<NN, 256, 0, stream>>>(hb, tmp, nullptr, nullptr, ln2_g + l*HID, ln2_b + l*HID, hb, 768, 1e-12f, 0);
    }

    // ---- 6. output head ----
    outproj_k<<<(NN*5 + 255)/256, 256, 0, stream>>>(hb, Wout, bout, outp);
}

// Round 2
// 8021.601 us; speedup vs baseline: 2.4171x; 2.4171x over previous
//
#include <hip/hip_runtime.h>
#include <hip/hip_bf16.h>
#include <math.h>

#define NN   4096
#define EE   65536
#define HID  768
#define SEQ  512
#define HDM  64
#define FFD  3072

typedef __attribute__((ext_vector_type(8))) short bf16x8;
typedef __attribute__((ext_vector_type(4))) float f32x4;

#define GLD16(gp, lp) __builtin_amdgcn_global_load_lds( \
    (__attribute__((address_space(1))) void*)(gp), \
    (__attribute__((address_space(3))) void*)(lp), 16, 0, 0)

// ---------- helpers ----------
__device__ __forceinline__ unsigned fenc(float f){
    unsigned u = __float_as_uint(f);
    return (u & 0x80000000u) ? ~u : (u | 0x80000000u);
}
__device__ __forceinline__ float fdec(unsigned e){
    unsigned u = (e & 0x80000000u) ? (e & 0x7FFFFFFFu) : ~e;
    return __uint_as_float(u);
}
__device__ __forceinline__ float gelu_exact(float x){
    return 0.5f * x * (1.0f + erff(x * 0.7071067811865476f));
}

// ---------- utility kernels ----------
__global__ void zero_f(float* p, int n){
    int i = blockIdx.x*256 + threadIdx.x;
    if (i < n) p[i] = 0.0f;
}
__global__ void zero_i(int* p, int n){
    int i = blockIdx.x*256 + threadIdx.x;
    if (i < n) p[i] = 0;
}
__global__ void copy_i(const int* s, int* d, int n){
    int i = blockIdx.x*256 + threadIdx.x;
    if (i < n) d[i] = s[i];
}

// ---------- fp32 -> bf16 flat convert ----------
__global__ void cvt_k(const float* __restrict__ s, __hip_bfloat16* __restrict__ d, int n){
    int i = (blockIdx.x*256 + threadIdx.x) * 4;
    if (i < n){
        float4 v = *(const float4*)(s + i);
        d[i]   = __float2bfloat16(v.x);
        d[i+1] = __float2bfloat16(v.y);
        d[i+2] = __float2bfloat16(v.z);
        d[i+3] = __float2bfloat16(v.w);
    }
}

// ---------- transpose + convert: W[K][N] f32 -> WT[Npad][K] bf16 (pad rows zero) ----------
__global__ __launch_bounds__(256) void tconv_k(const float* __restrict__ src,
    __hip_bfloat16* __restrict__ dst, int K, int N, long sStride, long dStride)
{
    src += (long)blockIdx.z * sStride; dst += (long)blockIdx.z * dStride;
    const int nb = blockIdx.x * 32, kb = blockIdx.y * 32;
    __shared__ float tile[32][33];
    const int t = threadIdx.x, r = t >> 3, c4 = (t & 7) * 4;
    if (nb < N){
        float4 v = *(const float4*)(src + (long)(kb + r)*N + nb + c4);
        tile[r][c4] = v.x; tile[r][c4+1] = v.y; tile[r][c4+2] = v.z; tile[r][c4+3] = v.w;
    }
    __syncthreads();
    __hip_bfloat16* dp = dst + (long)(nb + r)*K + kb + c4;
    if (nb < N){
        #pragma unroll
        for (int jj = 0; jj < 4; jj++) dp[jj] = __float2bfloat16(tile[c4 + jj][r]);
    } else {
        #pragma unroll
        for (int jj = 0; jj < 4; jj++) dp[jj] = __float2bfloat16(0.0f);
    }
}

// ---------- pack qkv bias ----------
__global__ void packb_k(const float* __restrict__ bq, const float* __restrict__ bk,
                        const float* __restrict__ bv, float* __restrict__ qb){
    int i = blockIdx.x*256 + threadIdx.x;
    if (i >= 12*2304) return;
    int l = i / 2304, c = i % 2304;
    float v = (c < 768) ? bq[l*768 + c] : (c < 1536) ? bk[l*768 + c - 768] : bv[l*768 + c - 1536];
    qb[i] = v;
}

// ---------- bf16 MFMA GEMM: C = act(A @ Bt^T + bias) ----------
// A: M x K bf16 (lda), Bt: N x K bf16 (ldb=K-stride), M = grid.y*128, N%? guarded, K%32==0.
template<int ACT, int WF32, int WBF16>   // ACT: 0 none, 1 relu, 2 gelu
__global__ __launch_bounds__(256) void bgemm_k(
    const __hip_bfloat16* __restrict__ A, const __hip_bfloat16* __restrict__ Bt,
    const float* __restrict__ bias, float* __restrict__ C, __hip_bfloat16* __restrict__ Cb,
    int N, int K, int lda, int ldb, int ldc, int ldcb)
{
    __shared__ __hip_bfloat16 As[128*32];
    __shared__ __hip_bfloat16 Bs[128*32];
    const int t = threadIdx.x;
    const int bm = blockIdx.y * 128, bn = blockIdx.x * 128;
    const int lrow = t >> 2, kch = (t & 3) * 8;
    const int wave = t >> 6, lane = t & 63;
    const int quad = lane >> 4, l16 = lane & 15;
    const int wm = (wave >> 1) * 64, wn = (wave & 1) * 64;

    const __hip_bfloat16* Ag0 = A + (long)(bm + lrow) * lda + kch;
    const __hip_bfloat16* Ag1 = Ag0 + 64L * lda;
    const __hip_bfloat16* Bg0 = Bt + (long)(bn + lrow) * ldb + kch;
    const __hip_bfloat16* Bg1 = Bg0 + 64L * ldb;
    __hip_bfloat16* lA0 = &As[(wave * 16) * 32];
    __hip_bfloat16* lA1 = &As[(64 + wave * 16) * 32];
    __hip_bfloat16* lB0 = &Bs[(wave * 16) * 32];
    __hip_bfloat16* lB1 = &Bs[(64 + wave * 16) * 32];

    f32x4 acc[4][4];
    #pragma unroll
    for (int i = 0; i < 4; i++)
        #pragma unroll
        for (int j = 0; j < 4; j++) acc[i][j] = (f32x4){0.f,0.f,0.f,0.f};

    for (int k0 = 0; k0 < K; k0 += 32){
        GLD16(Ag0 + k0, lA0);
        GLD16(Ag1 + k0, lA1);
        GLD16(Bg0 + k0, lB0);
        GLD16(Bg1 + k0, lB1);
        __syncthreads();
        bf16x8 af[4], bfr[4];
        #pragma unroll
        for (int i = 0; i < 4; i++)
            af[i] = *(const bf16x8*)&As[(wm + i*16 + l16)*32 + quad*8];
        #pragma unroll
        for (int j = 0; j < 4; j++)
            bfr[j] = *(const bf16x8*)&Bs[(wn + j*16 + l16)*32 + quad*8];
        #pragma unroll
        for (int i = 0; i < 4; i++)
            #pragma unroll
            for (int j = 0; j < 4; j++)
                acc[i][j] = __builtin_amdgcn_mfma_f32_16x16x32_bf16(af[i], bfr[j], acc[i][j], 0, 0, 0);
        __syncthreads();
    }

    #pragma unroll
    for (int i = 0; i < 4; i++){
        int row = bm + wm + i*16 + quad*4;
        #pragma unroll
        for (int j = 0; j < 4; j++){
            int col = bn + wn + j*16 + l16;
            if (col < N){
                float bv = bias ? bias[col] : 0.0f;
                #pragma unroll
                for (int r = 0; r < 4; r++){
                    float v = acc[i][j][r] + bv;
                    if (ACT == 1) v = fmaxf(v, 0.0f);
                    if (ACT == 2) v = gelu_exact(v);
                    if (WF32)  C[(long)(row + r)*ldc + col] = v;
                    if (WBF16) Cb[(long)(row + r)*ldcb + col] = __float2bfloat16(v);
                }
            }
        }
    }
}

// ---------- spatial embedding gather -> bf16 feat[:,384:768] ----------
__global__ void spat_k(const int* __restrict__ bbox, const float* __restrict__ Ex,
                       const float* __restrict__ Ey, __hip_bfloat16* __restrict__ feat)
{
    int idx = blockIdx.x*256 + threadIdx.x;
    if (idx >= NN*384) return;
    int n = idx / 384, j = idx % 384;
    int q = j / 96, jj = j % 96;
    const float* tab = (q == 0 || q == 2) ? Ex : Ey;
    int bi = bbox[n*4 + q];
    feat[(long)n*1536 + 384 + j] = __float2bfloat16(tab[bi*96 + jj]);
}

// ---------- CSR build ----------
__global__ void count_k(const int* __restrict__ dst, const float* __restrict__ ea,
                        int* __restrict__ cnt, float* __restrict__ sumea)
{
    int e = blockIdx.x*256 + threadIdx.x;
    if (e >= EE) return;
    int d = dst[e];
    atomicAdd(&cnt[d], 1);
    atomicAdd(&sumea[d], ea[e]);
}
__global__ __launch_bounds__(256) void scan_k(const int* __restrict__ cnt, int* __restrict__ offs)
{
    __shared__ int part[256];
    int t = threadIdx.x;
    int base = t*16;
    int loc[16]; int s = 0;
    #pragma unroll
    for (int i = 0; i < 16; i++){ loc[i] = s; s += cnt[base + i]; }
    part[t] = s;
    __syncthreads();
    for (int off = 1; off < 256; off <<= 1){
        int v = (t >= off) ? part[t - off] : 0;
        __syncthreads();
        part[t] += v;
        __syncthreads();
    }
    int pre = (t == 0) ? 0 : part[t-1];
    #pragma unroll
    for (int i = 0; i < 16; i++) offs[base + i] = pre + loc[i];
    if (t == 255) offs[NN] = part[255];
}
__global__ void loopea_k(const int* __restrict__ cnt, float* __restrict__ sumea)
{
    int i = blockIdx.x*256 + threadIdx.x;
    if (i < NN) sumea[i] = sumea[i] / fmaxf((float)cnt[i], 1.0f);
}
__global__ void fill_k(const int* __restrict__ dst, int* __restrict__ pos, int* __restrict__ eid)
{
    int e = blockIdx.x*256 + threadIdx.x;
    if (e >= EE) return;
    int d = dst[e];
    int idx = atomicAdd(&pos[d], 1);
    eid[idx] = e;
}

// ---------- GAT per-node attention coefficients ----------
__global__ __launch_bounds__(64) void headprep_k(
    const float* __restrict__ h, int ldh, const float* __restrict__ as_,
    const float* __restrict__ ad_, float* __restrict__ asrc, float* __restrict__ adst)
{
    int n = blockIdx.x, lane = threadIdx.x;
    int c0 = lane * 12;
    float s = 0.f, d = 0.f;
    #pragma unroll
    for (int i = 0; i < 12; i++){
        float hv = h[(long)n*ldh + c0 + i];
        s += hv * as_[c0 + i];
        d += hv * ad_[c0 + i];
    }
    #pragma unroll
    for (int o = 1; o < 8; o <<= 1){
        s += __shfl_xor(s, o, 64);
        d += __shfl_xor(d, o, 64);
    }
    if ((lane & 7) == 0){
        int gh = lane >> 3;
        asrc[n*8 + gh] = s;
        adst[n*8 + gh] = d;
    }
}

// ---------- GAT aggregation (one block per destination node) ----------
__global__ __launch_bounds__(256) void gatagg_k(
    const float* __restrict__ h, int ldh,
    const float* __restrict__ asrc, const float* __restrict__ adst,
    const int* __restrict__ src, const float* __restrict__ ea, const float* __restrict__ loopea,
    const int* __restrict__ offs, const int* __restrict__ eid,
    const float* __restrict__ We, const float* __restrict__ ae,
    const float* __restrict__ bias, float* __restrict__ outg)
{
    int n = blockIdx.x, t = threadIdx.x;
    __shared__ float Sh[8], adn[8], alself[8], exself[8], den[8];
    __shared__ unsigned me[8];
    __shared__ float exs[32][8];
    __shared__ int   srcs[32];

    if (t < 8){
        float s = 0.f;
        for (int cc = 0; cc < 96; cc++) s += We[t*96 + cc] * ae[t*96 + cc];
        Sh[t] = s;
        adn[t] = adst[n*8 + t];
        float al = asrc[n*8 + t] + adn[t] + loopea[n] * s;
        al = (al > 0.f) ? al : 0.2f * al;
        alself[t] = al;
        me[t] = fenc(al);
        den[t] = 0.f;
    }
    __syncthreads();
    int e0 = offs[n], deg = offs[n+1] - e0;
    for (int idx = t; idx < deg*8; idx += 256){
        int ei_ = idx >> 3, gh = idx & 7;
        int e = eid[e0 + ei_];
        int sn = src[e];
        float al = asrc[sn*8 + gh] + adn[gh] + ea[e]*Sh[gh];
        al = (al > 0.f) ? al : 0.2f * al;
        atomicMax(&me[gh], fenc(al));
    }
    __syncthreads();
    if (t < 8){
        float es = expf(alself[t] - fdec(me[t]));
        exself[t] = es;
        den[t] = es;
    }
    __syncthreads();

    int cs[3], ghc[3];
    float acc[3];
    #pragma unroll
    for (int i = 0; i < 3; i++){
        cs[i] = t + i*256;
        ghc[i] = cs[i] / 96;
        acc[i] = exself[ghc[i]] * h[(long)n*ldh + cs[i]];
    }
    const int mygh = t >> 5, le = t & 31;
    const float m_my = fdec(me[mygh]);
    float den_local = 0.f;

    for (int c0 = 0; c0 < deg; c0 += 32){
        int cnt = min(32, deg - c0);
        float ex = 0.f;
        if (le < cnt){
            int e = eid[e0 + c0 + le];
            int sn = src[e];
            if (mygh == 0) srcs[le] = sn;
            float al = asrc[sn*8 + mygh] + adn[mygh] + ea[e]*Sh[mygh];
            al = (al > 0.f) ? al : 0.2f * al;
            ex = expf(al - m_my);
            den_local += ex;
        }
        exs[le][mygh] = ex;
        __syncthreads();
        for (int j = 0; j < cnt; j++){
            const float* hp = h + (long)srcs[j]*ldh;
            #pragma unroll
            for (int i = 0; i < 3; i++) acc[i] += exs[j][ghc[i]] * hp[cs[i]];
        }
        __syncthreads();
    }
    atomicAdd(&den[mygh], den_local);
    __syncthreads();
    #pragma unroll
    for (int i = 0; i < 3; i++){
        float o = acc[i] / (den[ghc[i]] + 1e-16f) + bias[cs[i]];
        outg[(long)n*HID + cs[i]] += o;
    }
}

// ---------- LayerNorm with optional f32 + bf16 outputs ----------
__global__ __launch_bounds__(256) void ln_k(
    const float* __restrict__ in1, const float* __restrict__ in2,
    const float* __restrict__ pos, const float* __restrict__ typ,
    const float* __restrict__ g, const float* __restrict__ be,
    float* __restrict__ outf, int ldo, __hip_bfloat16* __restrict__ outb, int ldob,
    float eps, int dorelu)
{
    int row = blockIdx.x, t = threadIdx.x;
    float v[3];
    #pragma unroll
    for (int i = 0; i < 3; i++){
        int c = t + i*256;
        float x = in1[(long)row*HID + c];
        if (in2) x += in2[(long)row*HID + c];
        if (pos) x += pos[(row & (SEQ-1))*HID + c] + typ[c];
        if (dorelu) x = fmaxf(x, 0.0f);
        v[i] = x;
    }
    float s1 = v[0] + v[1] + v[2];
    float s2 = v[0]*v[0] + v[1]*v[1] + v[2]*v[2];
    #pragma unroll
    for (int o = 32; o > 0; o >>= 1){
        s1 += __shfl_down(s1, o, 64);
        s2 += __shfl_down(s2, o, 64);
    }
    __shared__ float red[8];
    int wid = t >> 6, lane = t & 63;
    if (lane == 0){ red[wid] = s1; red[4 + wid] = s2; }
    __syncthreads();
    if (t == 0){
        red[0] = red[0]+red[1]+red[2]+red[3];
        red[4] = red[4]+red[5]+red[6]+red[7];
    }
    __syncthreads();
    float mu  = red[0] * (1.0f/768.0f);
    float var = fmaxf(red[4] * (1.0f/768.0f) - mu*mu, 0.0f);
    float r = rsqrtf(var + eps);
    #pragma unroll
    for (int i = 0; i < 3; i++){
        int c = t + i*256;
        float y = (v[i] - mu)*r*g[c] + be[c];
        if (outf) outf[(long)row*ldo + c] = y;
        if (outb) outb[(long)row*ldob + c] = __float2bfloat16(y);
    }
}

// ---------- attention on packed QKV [N][2304]; out bf16 [N][768] ----------
__global__ __launch_bounds__(256) void attn_k(
    const float* __restrict__ QKV, __hip_bfloat16* __restrict__ Ob)
{
    const int q0 = blockIdx.x * 32;
    const int hh = blockIdx.y;
    const int b  = blockIdx.z;
    __shared__ float qs[32][HDM];
    __shared__ float kv[64][HDM + 4];
    __shared__ float sc[32][SEQ];
    const int t = threadIdx.x;
    const long rowbase = (long)b * SEQ;
    const int hoff = hh * HDM;

    { // load Q tile
        int r = t >> 3, d0 = (t & 7) * 8;
        const float* s = QKV + (rowbase + q0 + r) * 2304 + hoff + d0;
        *(float4*)&qs[r][d0]     = *(const float4*)s;
        *(float4*)&qs[r][d0 + 4] = *(const float4*)(s + 4);
    }
    __syncthreads();
    const int q = t >> 3, kk0 = t & 7;
    for (int kc = 0; kc < SEQ; kc += 64){
        { // load K chunk
            int r = t >> 2, d0 = (t & 3) * 16;
            const float* s = QKV + (rowbase + kc + r) * 2304 + 768 + hoff + d0;
            *(float4*)&kv[r][d0]      = *(const float4*)s;
            *(float4*)&kv[r][d0 + 4]  = *(const float4*)(s + 4);
            *(float4*)&kv[r][d0 + 8]  = *(const float4*)(s + 8);
            *(float4*)&kv[r][d0 + 12] = *(const float4*)(s + 12);
        }
        __syncthreads();
        for (int kk = kk0; kk < 64; kk += 8){
            float acc = 0.f;
            #pragma unroll
            for (int d4 = 0; d4 < HDM; d4 += 4){
                float4 qv = *(const float4*)&qs[q][d4];
                float4 kvv = *(const float4*)&kv[kk][d4];
                acc += qv.x*kvv.x + qv.y*kvv.y + qv.z*kvv.z + qv.w*kvv.w;
            }
            sc[q][kc + kk] = acc * 0.125f;
        }
        __syncthreads();
    }
    { // softmax
        int r = t >> 3, sub = t & 7;
        float m = -1e30f;
        for (int j = sub; j < SEQ; j += 8) m = fmaxf(m, sc[r][j]);
        #pragma unroll
        for (int o = 1; o < 8; o <<= 1) m = fmaxf(m, __shfl_xor(m, o, 64));
        float s = 0.f;
        for (int j = sub; j < SEQ; j += 8){
            float p = expf(sc[r][j] - m);
            sc[r][j] = p; s += p;
        }
        #pragma unroll
        for (int o = 1; o < 8; o <<= 1) s += __shfl_xor(s, o, 64);
        float inv = 1.0f / s;
        for (int j = sub; j < SEQ; j += 8) sc[r][j] *= inv;
    }
    __syncthreads();
    float acc[8] = {0,0,0,0,0,0,0,0};
    const int d0 = (t & 7) * 8;
    for (int kc = 0; kc < SEQ; kc += 64){
        { // load V chunk
            int r = t >> 2, dd = (t & 3) * 16;
            const float* s = QKV + (rowbase + kc + r) * 2304 + 1536 + hoff + dd;
            *(float4*)&kv[r][dd]      = *(const float4*)s;
            *(float4*)&kv[r][dd + 4]  = *(const float4*)(s + 4);
            *(float4*)&kv[r][dd + 8]  = *(const float4*)(s + 8);
            *(float4*)&kv[r][dd + 12] = *(const float4*)(s + 12);
        }
        __syncthreads();
        for (int j = 0; j < 64; j++){
            float p = sc[q][kc + j];
            float4 v0 = *(const float4*)&kv[j][d0];
            float4 v1 = *(const float4*)&kv[j][d0 + 4];
            acc[0] += p*v0.x; acc[1] += p*v0.y; acc[2] += p*v0.z; acc[3] += p*v0.w;
            acc[4] += p*v1.x; acc[5] += p*v1.y; acc[6] += p*v1.z; acc[7] += p*v1.w;
        }
        __syncthreads();
    }
    __hip_bfloat16* op = Ob + (rowbase + q0 + q) * 768 + hoff + d0;
    #pragma unroll
    for (int r = 0; r < 8; r++) op[r] = __float2bfloat16(acc[r]);
}

// ---------- final projection 768 -> 5 ----------
__global__ void outproj_k(const float* __restrict__ h, const float* __restrict__ W,
                          const float* __restrict__ b, float* __restrict__ out)
{
    int idx = blockIdx.x*256 + threadIdx.x;
    if (idx >= NN*5) return;
    int n = idx / 5, o = idx % 5;
    float acc = b[o];
    for (int k = 0; k < HID; k++) acc += h[(long)n*HID + k] * W[k*5 + o];
    out[idx] = acc;
}

// ---------- host launch ----------
extern "C" void kernel_launch(void* const* d_in, const int* in_sizes, int n_in,
                              void* d_out, int out_size, void* d_ws, size_t ws_size,
                              hipStream_t stream)
{
    const float* text_x = (const float*)d_in[0];
    const float* img_x  = (const float*)d_in[1];
    const int*   bbox   = (const int*)d_in[2];
    const int*   ei[3]  = {(const int*)d_in[3], (const int*)d_in[4], (const int*)d_in[5]};
    const float* ea[3]  = {(const float*)d_in[6], (const float*)d_in[7], (const float*)d_in[8]};
    const float* Wt = (const float*)d_in[9];   const float* bt = (const float*)d_in[10];
    const float* Wi = (const float*)d_in[11];  const float* bi = (const float*)d_in[12];
    const float* Ex = (const float*)d_in[13];  const float* Ey = (const float*)d_in[14];
    const float* Wc = (const float*)d_in[15];  const float* bc = (const float*)d_in[16];
    const float* gat_W  = (const float*)d_in[17];
    const float* gat_as = (const float*)d_in[18];
    const float* gat_ad = (const float*)d_in[19];
    const float* gat_We = (const float*)d_in[20];
    const float* gat_ae = (const float*)d_in[21];
    const float* gat_bias = (const float*)d_in[22];
    const float* ln_g = (const float*)d_in[23]; const float* ln_b = (const float*)d_in[24];
    const float* Wcomb = (const float*)d_in[25]; const float* bcomb = (const float*)d_in[26];
    const float* pos_emb = (const float*)d_in[27]; const float* type_emb = (const float*)d_in[28];
    const float* emb_g = (const float*)d_in[29]; const float* emb_b = (const float*)d_in[30];
    const float* Wq = (const float*)d_in[31]; const float* Wk = (const float*)d_in[32];
    const float* Wv = (const float*)d_in[33]; const float* Wo = (const float*)d_in[34];
    const float* W1 = (const float*)d_in[35]; const float* W2 = (const float*)d_in[36];
    const float* bq = (const float*)d_in[37]; const float* bk = (const float*)d_in[38];
    const float* bv = (const float*)d_in[39]; const float* bo = (const float*)d_in[40];
    const float* bff1 = (const float*)d_in[41]; const float* bff2 = (const float*)d_in[42];
    const float* ln1_g = (const float*)d_in[43]; const float* ln1_b = (const float*)d_in[44];
    const float* ln2_g = (const float*)d_in[45]; const float* ln2_b = (const float*)d_in[46];
    const float* Wout = (const float*)d_in[47]; const float* bout = (const float*)d_in[48];
    float* outp = (float*)d_out;

    // ---- workspace carve ----
    char* p0 = (char*)d_ws; char* p = p0;
    auto carve = [&](size_t b)->char*{ char* r = p; p += (b + 255) & ~(size_t)255; return r; };

    __hip_bfloat16* gatWT  = (__hip_bfloat16*)carve(6L*768*768*2);
    __hip_bfloat16* WcT    = (__hip_bfloat16*)carve(768L*768*2);
    __hip_bfloat16* WcombT = (__hip_bfloat16*)carve(768L*1536*2);
    __hip_bfloat16* WtT    = (__hip_bfloat16*)carve(256L*768*2);
    __hip_bfloat16* WiT    = (__hip_bfloat16*)carve(256L*512*2);
    float* qbias           = (float*)carve(12L*2304*4);
    __hip_bfloat16* featb  = (__hip_bfloat16*)carve(4096L*1536*2);
    float* hb              = (float*)carve(4096L*768*4);
    __hip_bfloat16* hbb    = (__hip_bfloat16*)carve(4096L*768*2);
    char* U                = carve(56623104);   // union region (GAT needs 56.6MB, BERT 44MB)
    float* asrc = (float*)carve(4096L*8*4);
    float* adst = (float*)carve(4096L*8*4);
    float* sumea= (float*)carve(3L*4096*4);
    int* cnt    = (int*)carve(3L*4096*4);
    int* offs   = (int*)carve(3L*4097*4);
    int* posb   = (int*)carve(4096L*4);
    int* eid    = (int*)carve(3L*65536*4);

    size_t used = (size_t)(p - p0);
    size_t bert_all = 42467328UL + 14155776UL + 56623104UL + 56623104UL + 2048UL;
    bool big = (ws_size > used) && ((ws_size - used) >= bert_all);
    __hip_bfloat16* WqkvT = (__hip_bfloat16*)carve(big ? 12L*2304*768*2 : 2304L*768*2);
    __hip_bfloat16* WoT   = (__hip_bfloat16*)carve(big ? 12L*768*768*2  : 768L*768*2);
    __hip_bfloat16* W1T   = (__hip_bfloat16*)carve(big ? 12L*3072*768*2 : 3072L*768*2);
    __hip_bfloat16* W2T   = (__hip_bfloat16*)carve(big ? 12L*768*3072*2 : 768L*3072*2);
    long sQ = big ? 2304L*768 : 0, sO = big ? 768L*768 : 0;
    long s1 = big ? 3072L*768 : 0, s2 = big ? 768L*3072 : 0;

    // U overlays (lifetimes verified: see round-1 journal)
    __hip_bfloat16* xb_bf   = (__hip_bfloat16*)U;                  // GAT input (bf16)
    float*          outg    = (float*)(U + 6291456);               // GAT accum
    float*          hbuf    = (float*)(U + 18874368);              // GAT h (4096x2304 f32)
    __hip_bfloat16* text_bf = (__hip_bfloat16*)(U + 12582912);
    __hip_bfloat16* img_bf  = (__hip_bfloat16*)(U + 18874368);
    float*          tmp     = (float*)U;                           // BERT gemm f32 out
    __hip_bfloat16* ffb     = (__hip_bfloat16*)(U + 12582912);     // FF intermediate bf16
    float*          qkv     = (float*)U;                           // 4096x2304 f32
    __hip_bfloat16* ctxb    = (__hip_bfloat16*)(U + 37748736);     // attn out bf16

    // ---- 0. weight conversions ----
    cvt_k<<<3072, 256, 0, stream>>>(text_x, text_bf, NN*768);
    cvt_k<<<2048, 256, 0, stream>>>(img_x,  img_bf,  NN*512);
    tconv_k<<<dim3(8,24,1),  256, 0, stream>>>(Wt, WtT, 768, 192, 0, 0);
    tconv_k<<<dim3(8,16,1),  256, 0, stream>>>(Wi, WiT, 512, 192, 0, 0);
    tconv_k<<<dim3(24,24,1), 256, 0, stream>>>(Wc, WcT, 768, 768, 0, 0);
    tconv_k<<<dim3(24,48,1), 256, 0, stream>>>(Wcomb, WcombT, 1536, 768, 0, 0);
    tconv_k<<<dim3(24,24,6), 256, 0, stream>>>(gat_W, gatWT, 768, 768, 589824, 589824);
    packb_k<<<108, 256, 0, stream>>>(bq, bk, bv, qbias);
    if (big){
        tconv_k<<<dim3(24,24,12), 256, 0, stream>>>(Wq, WqkvT,           768, 768, 589824, 1769472);
        tconv_k<<<dim3(24,24,12), 256, 0, stream>>>(Wk, WqkvT + 589824,  768, 768, 589824, 1769472);
        tconv_k<<<dim3(24,24,12), 256, 0, stream>>>(Wv, WqkvT + 1179648, 768, 768, 589824, 1769472);
        tconv_k<<<dim3(24,24,12), 256, 0, stream>>>(Wo, WoT, 768, 768,  589824, 589824);
        tconv_k<<<dim3(96,24,12), 256, 0, stream>>>(W1, W1T, 768, 3072, 2359296, 2359296);
        tconv_k<<<dim3(24,96,12), 256, 0, stream>>>(W2, W2T, 3072, 768, 2359296, 2359296);
    }

    // ---- 1. input projections ----
    bgemm_k<0,0,1><<<dim3(2,32), 256, 0, stream>>>(text_bf, WtT, bt, nullptr, featb,     192, 768, 768, 768, 0, 1536);
    bgemm_k<0,0,1><<<dim3(2,32), 256, 0, stream>>>(img_bf,  WiT, bi, nullptr, featb+192, 192, 512, 512, 512, 0, 1536);
    spat_k<<<6144, 256, 0, stream>>>(bbox, Ex, Ey, featb);
    bgemm_k<1,0,1><<<dim3(6,32), 256, 0, stream>>>(featb, WcT, bc, nullptr, xb_bf, 768, 768, 1536, 768, 0, 768);

    // ---- 2. CSR per edge type ----
    zero_i<<<48, 256, 0, stream>>>(cnt, 3*NN);
    zero_f<<<48, 256, 0, stream>>>(sumea, 3*NN);
    for (int t = 0; t < 3; t++){
        count_k<<<EE/256, 256, 0, stream>>>(ei[t] + EE, ea[t], cnt + t*NN, sumea + t*NN);
        scan_k<<<1, 256, 0, stream>>>(cnt + t*NN, offs + t*(NN+1));
        loopea_k<<<NN/256, 256, 0, stream>>>(cnt + t*NN, sumea + t*NN);
        copy_i<<<NN/256, 256, 0, stream>>>(offs + t*(NN+1), posb, NN);
        fill_k<<<EE/256, 256, 0, stream>>>(ei[t] + EE, posb, eid + t*EE);
    }

    // ---- 3. GAT layers (fused 3-type GEMM, N=2304) ----
    for (int l = 0; l < 2; l++){
        zero_f<<<12288, 256, 0, stream>>>(outg, NN*HID);
        bgemm_k<0,1,0><<<dim3(18,32), 256, 0, stream>>>(xb_bf, gatWT + (long)l*1769472, nullptr,
                                                        hbuf, nullptr, 2304, 768, 768, 768, 2304, 0);
        for (int t = 0; t < 3; t++){
            int lt = l*3 + t;
            headprep_k<<<NN, 64, 0, stream>>>(hbuf + t*768, 2304, gat_as + lt*768, gat_ad + lt*768, asrc, adst);
            gatagg_k<<<NN, 256, 0, stream>>>(hbuf + t*768, 2304, asrc, adst, ei[t], ea[t], sumea + t*NN,
                                             offs + t*(NN+1), eid + t*EE,
                                             gat_We + lt*768, gat_ae + lt*768,
                                             gat_bias + lt*768, outg);
        }
        if (l == 0)
            ln_k<<<NN, 256, 0, stream>>>(outg, nullptr, nullptr, nullptr, ln_g, ln_b,
                                         nullptr, 0, xb_bf, 768, 1e-5f, 1);
        else
            ln_k<<<NN, 256, 0, stream>>>(outg, nullptr, nullptr, nullptr, ln_g + HID, ln_b + HID,
                                         nullptr, 0, featb + 768, 1536, 1e-5f, 1);
    }

    // ---- 4. comb + embedding LN ----
    bgemm_k<1,1,0><<<dim3(6,32), 256, 0, stream>>>(featb, WcombT, bcomb, tmp, nullptr,
                                                   768, 1536, 1536, 1536, 768, 0);
    ln_k<<<NN, 256, 0, stream>>>(tmp, nullptr, pos_emb, type_emb, emb_g, emb_b, hb, 768, hbb, 768, 1e-12f, 0);

    // ---- 5. BERT layers ----
    for (int l = 0; l < 12; l++){
        if (!big){
            tconv_k<<<dim3(24,24,1), 256, 0, stream>>>(Wq + (long)l*589824, WqkvT,           768, 768, 0, 0);
            tconv_k<<<dim3(24,24,1), 256, 0, stream>>>(Wk + (long)l*589824, WqkvT + 589824,  768, 768, 0, 0);
            tconv_k<<<dim3(24,24,1), 256, 0, stream>>>(Wv + (long)l*589824, WqkvT + 1179648, 768, 768, 0, 0);
            tconv_k<<<dim3(24,24,1), 256, 0, stream>>>(Wo + (long)l*589824, WoT, 768, 768, 0, 0);
            tconv_k<<<dim3(96,24,1), 256, 0, stream>>>(W1 + (long)l*2359296, W1T, 768, 3072, 0, 0);
            tconv_k<<<dim3(24,96,1), 256, 0, stream>>>(W2 + (long)l*2359296, W2T, 3072, 768, 0, 0);
        }
        const __hip_bfloat16* wq = WqkvT + l*sQ;
        const __hip_bfloat16* wo = WoT + l*sO;
        const __hip_bfloat16* w1 = W1T + l*s1;
        const __hip_bfloat16* w2 = W2T + l*s2;
        bgemm_k<0,1,0><<<dim3(18,32), 256, 0, stream>>>(hbb, wq, qbias + l*2304, qkv, nullptr,
                                                        2304, 768, 768, 768, 2304, 0);
        attn_k<<<dim3(16,12,8), 256, 0, stream>>>(qkv, ctxb);
        bgemm_k<0,1,0><<<dim3(6,32), 256, 0, stream>>>(ctxb, wo, bo + l*768, tmp, nullptr,
                                                       768, 768, 768, 768, 768, 0);
        ln_k<<<NN, 256, 0, stream>>>(hb, tmp, nullptr, nullptr, ln1_g + l*768, ln1_b + l*768,
                                     hb, 768, hbb, 768, 1e-12f, 0);
        bgemm_k<2,0,1><<<dim3(24,32), 256, 0, stream>>>(hbb, w1, bff1 + l*3072, nullptr, ffb,
                                                        3072, 768, 768, 768, 0, 3072);
        bgemm_k<0,1,0><<<dim3(6,32), 256, 0, stream>>>(ffb, w2, bff2 + l*768, tmp, nullptr,
                                                       768, 3072, 3072, 3072, 768, 0);
        ln_k<<<NN, 256, 0, stream>>>(hb, tmp, nullptr, nullptr, ln2_g + l*768, ln2_b + l*768,
                                     hb, 768, hbb, 768, 1e-12f, 0);
    }

    // ---- 6. output head ----
    outproj_k<<<80, 256, 0, stream>>>(hb, Wout, bout, outp);
}

// Round 3
// 3860.008 us; speedup vs baseline: 5.0231x; 2.0781x over previous
//
#include <hip/hip_runtime.h>
#include <hip/hip_bf16.h>
#include <math.h>

#define NN   4096
#define EE   65536
#define HID  768
#define SEQ  512
#define HDM  64
#define FFD  3072

typedef __attribute__((ext_vector_type(8))) short bf16x8;
typedef __attribute__((ext_vector_type(4))) float f32x4;

#define GLD16(gp, lp) __builtin_amdgcn_global_load_lds( \
    (__attribute__((address_space(1))) void*)(gp), \
    (__attribute__((address_space(3))) void*)(lp), 16, 0, 0)

// ---------- helpers ----------
__device__ __forceinline__ unsigned fenc(float f){
    unsigned u = __float_as_uint(f);
    return (u & 0x80000000u) ? ~u : (u | 0x80000000u);
}
__device__ __forceinline__ float fdec(unsigned e){
    unsigned u = (e & 0x80000000u) ? (e & 0x7FFFFFFFu) : ~e;
    return __uint_as_float(u);
}
__device__ __forceinline__ float gelu_exact(float x){
    return 0.5f * x * (1.0f + erff(x * 0.7071067811865476f));
}
__device__ __forceinline__ float bf2f(short s){
    return __uint_as_float(((unsigned)(unsigned short)s) << 16);
}
__device__ __forceinline__ short f2bf(float f){
    __hip_bfloat16 h = __float2bfloat16(f);
    return *(short*)&h;
}

// ---------- utility kernels ----------
__global__ void zero_f(float* p, int n){
    int i = blockIdx.x*256 + threadIdx.x;
    if (i < n) p[i] = 0.0f;
}
__global__ void zero_i(int* p, int n){
    int i = blockIdx.x*256 + threadIdx.x;
    if (i < n) p[i] = 0;
}
__global__ void copy_i(const int* s, int* d, int n){
    int i = blockIdx.x*256 + threadIdx.x;
    if (i < n) d[i] = s[i];
}

// ---------- fp32 -> bf16 flat convert ----------
__global__ void cvt_k(const float* __restrict__ s, __hip_bfloat16* __restrict__ d, int n){
    int i = (blockIdx.x*256 + threadIdx.x) * 4;
    if (i < n){
        float4 v = *(const float4*)(s + i);
        d[i]   = __float2bfloat16(v.x);
        d[i+1] = __float2bfloat16(v.y);
        d[i+2] = __float2bfloat16(v.z);
        d[i+3] = __float2bfloat16(v.w);
    }
}

// ---------- transpose + convert: W[K][N] f32 -> WT[Npad][K] bf16 (pad rows zero) ----------
__global__ __launch_bounds__(256) void tconv_k(const float* __restrict__ src,
    __hip_bfloat16* __restrict__ dst, int K, int N, long sStride, long dStride)
{
    src += (long)blockIdx.z * sStride; dst += (long)blockIdx.z * dStride;
    const int nb = blockIdx.x * 32, kb = blockIdx.y * 32;
    __shared__ float tile[32][33];
    const int t = threadIdx.x, r = t >> 3, c4 = (t & 7) * 4;
    if (nb < N){
        float4 v = *(const float4*)(src + (long)(kb + r)*N + nb + c4);
        tile[r][c4] = v.x; tile[r][c4+1] = v.y; tile[r][c4+2] = v.z; tile[r][c4+3] = v.w;
    }
    __syncthreads();
    __hip_bfloat16* dp = dst + (long)(nb + r)*K + kb + c4;
    if (nb < N){
        #pragma unroll
        for (int jj = 0; jj < 4; jj++) dp[jj] = __float2bfloat16(tile[c4 + jj][r]);
    } else {
        #pragma unroll
        for (int jj = 0; jj < 4; jj++) dp[jj] = __float2bfloat16(0.0f);
    }
}

// ---------- pack qkv bias ----------
__global__ void packb_k(const float* __restrict__ bq, const float* __restrict__ bk,
                        const float* __restrict__ bv, float* __restrict__ qb){
    int i = blockIdx.x*256 + threadIdx.x;
    if (i >= 12*2304) return;
    int l = i / 2304, c = i % 2304;
    float v = (c < 768) ? bq[l*768 + c] : (c < 1536) ? bk[l*768 + c - 768] : bv[l*768 + c - 1536];
    qb[i] = v;
}

// ---------- bf16 MFMA GEMM: C = act(A @ Bt^T + bias) ----------
template<int ACT, int WF32, int WBF16>   // ACT: 0 none, 1 relu, 2 gelu
__global__ __launch_bounds__(256) void bgemm_k(
    const __hip_bfloat16* __restrict__ A, const __hip_bfloat16* __restrict__ Bt,
    const float* __restrict__ bias, float* __restrict__ C, __hip_bfloat16* __restrict__ Cb,
    int N, int K, int lda, int ldb, int ldc, int ldcb)
{
    __shared__ __hip_bfloat16 As[128*32];
    __shared__ __hip_bfloat16 Bs[128*32];
    const int t = threadIdx.x;
    const int bm = blockIdx.y * 128, bn = blockIdx.x * 128;
    const int lrow = t >> 2, kch = (t & 3) * 8;
    const int wave = t >> 6, lane = t & 63;
    const int quad = lane >> 4, l16 = lane & 15;
    const int wm = (wave >> 1) * 64, wn = (wave & 1) * 64;

    const __hip_bfloat16* Ag0 = A + (long)(bm + lrow) * lda + kch;
    const __hip_bfloat16* Ag1 = Ag0 + 64L * lda;
    const __hip_bfloat16* Bg0 = Bt + (long)(bn + lrow) * ldb + kch;
    const __hip_bfloat16* Bg1 = Bg0 + 64L * ldb;
    __hip_bfloat16* lA0 = &As[(wave * 16) * 32];
    __hip_bfloat16* lA1 = &As[(64 + wave * 16) * 32];
    __hip_bfloat16* lB0 = &Bs[(wave * 16) * 32];
    __hip_bfloat16* lB1 = &Bs[(64 + wave * 16) * 32];

    f32x4 acc[4][4];
    #pragma unroll
    for (int i = 0; i < 4; i++)
        #pragma unroll
        for (int j = 0; j < 4; j++) acc[i][j] = (f32x4){0.f,0.f,0.f,0.f};

    for (int k0 = 0; k0 < K; k0 += 32){
        GLD16(Ag0 + k0, lA0);
        GLD16(Ag1 + k0, lA1);
        GLD16(Bg0 + k0, lB0);
        GLD16(Bg1 + k0, lB1);
        __syncthreads();
        bf16x8 af[4], bfr[4];
        #pragma unroll
        for (int i = 0; i < 4; i++)
            af[i] = *(const bf16x8*)&As[(wm + i*16 + l16)*32 + quad*8];
        #pragma unroll
        for (int j = 0; j < 4; j++)
            bfr[j] = *(const bf16x8*)&Bs[(wn + j*16 + l16)*32 + quad*8];
        #pragma unroll
        for (int i = 0; i < 4; i++)
            #pragma unroll
            for (int j = 0; j < 4; j++)
                acc[i][j] = __builtin_amdgcn_mfma_f32_16x16x32_bf16(af[i], bfr[j], acc[i][j], 0, 0, 0);
        __syncthreads();
    }

    #pragma unroll
    for (int i = 0; i < 4; i++){
        int row = bm + wm + i*16 + quad*4;
        #pragma unroll
        for (int j = 0; j < 4; j++){
            int col = bn + wn + j*16 + l16;
            if (col < N){
                float bv = bias ? bias[col] : 0.0f;
                #pragma unroll
                for (int r = 0; r < 4; r++){
                    float v = acc[i][j][r] + bv;
                    if (ACT == 1) v = fmaxf(v, 0.0f);
                    if (ACT == 2) v = gelu_exact(v);
                    if (WF32)  C[(long)(row + r)*ldc + col] = v;
                    if (WBF16) Cb[(long)(row + r)*ldcb + col] = __float2bfloat16(v);
                }
            }
        }
    }
}

// ---------- spatial embedding gather -> bf16 feat[:,384:768] ----------
__global__ void spat_k(const int* __restrict__ bbox, const float* __restrict__ Ex,
                       const float* __restrict__ Ey, __hip_bfloat16* __restrict__ feat)
{
    int idx = blockIdx.x*256 + threadIdx.x;
    if (idx >= NN*384) return;
    int n = idx / 384, j = idx % 384;
    int q = j / 96, jj = j % 96;
    const float* tab = (q == 0 || q == 2) ? Ex : Ey;
    int bi = bbox[n*4 + q];
    feat[(long)n*1536 + 384 + j] = __float2bfloat16(tab[bi*96 + jj]);
}

// ---------- CSR build ----------
__global__ void count_k(const int* __restrict__ dst, const float* __restrict__ ea,
                        int* __restrict__ cnt, float* __restrict__ sumea)
{
    int e = blockIdx.x*256 + threadIdx.x;
    if (e >= EE) return;
    int d = dst[e];
    atomicAdd(&cnt[d], 1);
    atomicAdd(&sumea[d], ea[e]);
}
__global__ __launch_bounds__(256) void scan_k(const int* __restrict__ cnt, int* __restrict__ offs)
{
    __shared__ int part[256];
    int t = threadIdx.x;
    int base = t*16;
    int loc[16]; int s = 0;
    #pragma unroll
    for (int i = 0; i < 16; i++){ loc[i] = s; s += cnt[base + i]; }
    part[t] = s;
    __syncthreads();
    for (int off = 1; off < 256; off <<= 1){
        int v = (t >= off) ? part[t - off] : 0;
        __syncthreads();
        part[t] += v;
        __syncthreads();
    }
    int pre = (t == 0) ? 0 : part[t-1];
    #pragma unroll
    for (int i = 0; i < 16; i++) offs[base + i] = pre + loc[i];
    if (t == 255) offs[NN] = part[255];
}
__global__ void loopea_k(const int* __restrict__ cnt, float* __restrict__ sumea)
{
    int i = blockIdx.x*256 + threadIdx.x;
    if (i < NN) sumea[i] = sumea[i] / fmaxf((float)cnt[i], 1.0f);
}
__global__ void fill_k(const int* __restrict__ dst, int* __restrict__ pos, int* __restrict__ eid)
{
    int e = blockIdx.x*256 + threadIdx.x;
    if (e >= EE) return;
    int d = dst[e];
    int idx = atomicAdd(&pos[d], 1);
    eid[idx] = e;
}

// ---------- GAT per-node attention coefficients ----------
__global__ __launch_bounds__(64) void headprep_k(
    const float* __restrict__ h, int ldh, const float* __restrict__ as_,
    const float* __restrict__ ad_, float* __restrict__ asrc, float* __restrict__ adst)
{
    int n = blockIdx.x, lane = threadIdx.x;
    int c0 = lane * 12;
    float s = 0.f, d = 0.f;
    #pragma unroll
    for (int i = 0; i < 12; i++){
        float hv = h[(long)n*ldh + c0 + i];
        s += hv * as_[c0 + i];
        d += hv * ad_[c0 + i];
    }
    #pragma unroll
    for (int o = 1; o < 8; o <<= 1){
        s += __shfl_xor(s, o, 64);
        d += __shfl_xor(d, o, 64);
    }
    if ((lane & 7) == 0){
        int gh = lane >> 3;
        asrc[n*8 + gh] = s;
        adst[n*8 + gh] = d;
    }
}

// ---------- GAT aggregation (one block per destination node) ----------
__global__ __launch_bounds__(256) void gatagg_k(
    const float* __restrict__ h, int ldh,
    const float* __restrict__ asrc, const float* __restrict__ adst,
    const int* __restrict__ src, const float* __restrict__ ea, const float* __restrict__ loopea,
    const int* __restrict__ offs, const int* __restrict__ eid,
    const float* __restrict__ We, const float* __restrict__ ae,
    const float* __restrict__ bias, float* __restrict__ outg)
{
    int n = blockIdx.x, t = threadIdx.x;
    __shared__ float Sh[8], adn[8], alself[8], exself[8], den[8];
    __shared__ unsigned me[8];
    __shared__ float exs[32][8];
    __shared__ int   srcs[32];

    if (t < 8){
        float s = 0.f;
        for (int cc = 0; cc < 96; cc++) s += We[t*96 + cc] * ae[t*96 + cc];
        Sh[t] = s;
        adn[t] = adst[n*8 + t];
        float al = asrc[n*8 + t] + adn[t] + loopea[n] * s;
        al = (al > 0.f) ? al : 0.2f * al;
        alself[t] = al;
        me[t] = fenc(al);
        den[t] = 0.f;
    }
    __syncthreads();
    int e0 = offs[n], deg = offs[n+1] - e0;
    for (int idx = t; idx < deg*8; idx += 256){
        int ei_ = idx >> 3, gh = idx & 7;
        int e = eid[e0 + ei_];
        int sn = src[e];
        float al = asrc[sn*8 + gh] + adn[gh] + ea[e]*Sh[gh];
        al = (al > 0.f) ? al : 0.2f * al;
        atomicMax(&me[gh], fenc(al));
    }
    __syncthreads();
    if (t < 8){
        float es = expf(alself[t] - fdec(me[t]));
        exself[t] = es;
        den[t] = es;
    }
    __syncthreads();

    int cs[3], ghc[3];
    float acc[3];
    #pragma unroll
    for (int i = 0; i < 3; i++){
        cs[i] = t + i*256;
        ghc[i] = cs[i] / 96;
        acc[i] = exself[ghc[i]] * h[(long)n*ldh + cs[i]];
    }
    const int mygh = t >> 5, le = t & 31;
    const float m_my = fdec(me[mygh]);
    float den_local = 0.f;

    for (int c0 = 0; c0 < deg; c0 += 32){
        int cnt = min(32, deg - c0);
        float ex = 0.f;
        if (le < cnt){
            int e = eid[e0 + c0 + le];
            int sn = src[e];
            if (mygh == 0) srcs[le] = sn;
            float al = asrc[sn*8 + mygh] + adn[mygh] + ea[e]*Sh[mygh];
            al = (al > 0.f) ? al : 0.2f * al;
            ex = expf(al - m_my);
            den_local += ex;
        }
        exs[le][mygh] = ex;
        __syncthreads();
        for (int j = 0; j < cnt; j++){
            const float* hp = h + (long)srcs[j]*ldh;
            #pragma unroll
            for (int i = 0; i < 3; i++) acc[i] += exs[j][ghc[i]] * hp[cs[i]];
        }
        __syncthreads();
    }
    atomicAdd(&den[mygh], den_local);
    __syncthreads();
    #pragma unroll
    for (int i = 0; i < 3; i++){
        float o = acc[i] / (den[ghc[i]] + 1e-16f) + bias[cs[i]];
        outg[(long)n*HID + cs[i]] += o;
    }
}

// ---------- LayerNorm with optional f32 + bf16 outputs ----------
__global__ __launch_bounds__(256) void ln_k(
    const float* __restrict__ in1, const float* __restrict__ in2,
    const float* __restrict__ pos, const float* __restrict__ typ,
    const float* __restrict__ g, const float* __restrict__ be,
    float* __restrict__ outf, int ldo, __hip_bfloat16* __restrict__ outb, int ldob,
    float eps, int dorelu)
{
    int row = blockIdx.x, t = threadIdx.x;
    float v[3];
    #pragma unroll
    for (int i = 0; i < 3; i++){
        int c = t + i*256;
        float x = in1[(long)row*HID + c];
        if (in2) x += in2[(long)row*HID + c];
        if (pos) x += pos[(row & (SEQ-1))*HID + c] + typ[c];
        if (dorelu) x = fmaxf(x, 0.0f);
        v[i] = x;
    }
    float s1 = v[0] + v[1] + v[2];
    float s2 = v[0]*v[0] + v[1]*v[1] + v[2]*v[2];
    #pragma unroll
    for (int o = 32; o > 0; o >>= 1){
        s1 += __shfl_down(s1, o, 64);
        s2 += __shfl_down(s2, o, 64);
    }
    __shared__ float red[8];
    int wid = t >> 6, lane = t & 63;
    if (lane == 0){ red[wid] = s1; red[4 + wid] = s2; }
    __syncthreads();
    if (t == 0){
        red[0] = red[0]+red[1]+red[2]+red[3];
        red[4] = red[4]+red[5]+red[6]+red[7];
    }
    __syncthreads();
    float mu  = red[0] * (1.0f/768.0f);
    float var = fmaxf(red[4] * (1.0f/768.0f) - mu*mu, 0.0f);
    float r = rsqrtf(var + eps);
    #pragma unroll
    for (int i = 0; i < 3; i++){
        int c = t + i*256;
        float y = (v[i] - mu)*r*g[c] + be[c];
        if (outf) outf[(long)row*ldo + c] = y;
        if (outb) outb[(long)row*ldob + c] = __float2bfloat16(y);
    }
}

// ---------- MFMA flash attention on packed bf16 QKV [N][2304] ----------
// grid (SEQ/64, 12 heads, 8 batch), 256 threads = 4 waves; wave handles 16 q-rows.
__global__ __launch_bounds__(256) void attn2_k(
    const __hip_bfloat16* __restrict__ QKV, __hip_bfloat16* __restrict__ Ob)
{
    __shared__ short Qs[64][72];
    __shared__ short Ks[64][72];
    __shared__ short Vt[64][72];    // Vt[d][s]
    __shared__ short Ps[4][16][72]; // per-wave P (A-layout staging)

    const int t = threadIdx.x;
    const int wave = t >> 6, lane = t & 63;
    const int quad = lane >> 4, l16 = lane & 15;
    const int wm = wave * 16;
    const int q0 = blockIdx.x * 64;
    const long rowbase = (long)blockIdx.z * SEQ;
    const int hoff = blockIdx.y * HDM;
    const short* QKVs = (const short*)QKV;

    { // stage Q (fold softmax scale 1/8 — exact in bf16)
        int r = t >> 2, d0 = (t & 3) * 16;
        const short* s = QKVs + (rowbase + q0 + r) * 2304 + hoff + d0;
        bf16x8 v0 = *(const bf16x8*)s, v1 = *(const bf16x8*)(s + 8);
        #pragma unroll
        for (int i = 0; i < 8; i++){
            Qs[r][d0 + i]     = f2bf(bf2f(v0[i]) * 0.125f);
            Qs[r][d0 + 8 + i] = f2bf(bf2f(v1[i]) * 0.125f);
        }
    }

    f32x4 O[4];
    float m_[4], l_[4];
    #pragma unroll
    for (int j = 0; j < 4; j++) O[j] = (f32x4){0.f,0.f,0.f,0.f};
    #pragma unroll
    for (int r = 0; r < 4; r++){ m_[r] = -1e30f; l_[r] = 0.f; }

    for (int kc = 0; kc < SEQ; kc += 64){
        __syncthreads();   // previous chunk's LDS reads done
        { // K chunk (row-major = B-frag layout)
            int r = t >> 2, d0 = (t & 3) * 16;
            const short* s = QKVs + (rowbase + kc + r) * 2304 + 768 + hoff + d0;
            *(bf16x8*)&Ks[r][d0]     = *(const bf16x8*)s;
            *(bf16x8*)&Ks[r][d0 + 8] = *(const bf16x8*)(s + 8);
        }
        { // V chunk, transposed into Vt[d][s]
            int r = t >> 2, d0 = (t & 3) * 16;
            const short* s = QKVs + (rowbase + kc + r) * 2304 + 1536 + hoff + d0;
            bf16x8 v0 = *(const bf16x8*)s, v1 = *(const bf16x8*)(s + 8);
            #pragma unroll
            for (int i = 0; i < 8; i++){
                Vt[d0 + i][r]     = v0[i];
                Vt[d0 + 8 + i][r] = v1[i];
            }
        }
        __syncthreads();

        // S = Q K^T  (16 q-rows x 64 s-cols per wave)
        f32x4 S[4];
        #pragma unroll
        for (int j = 0; j < 4; j++) S[j] = (f32x4){0.f,0.f,0.f,0.f};
        #pragma unroll
        for (int st = 0; st < 2; st++){
            bf16x8 a = *(const bf16x8*)&Qs[wm + l16][quad*8 + st*32];
            #pragma unroll
            for (int j = 0; j < 4; j++){
                bf16x8 bk_ = *(const bf16x8*)&Ks[j*16 + l16][quad*8 + st*32];
                S[j] = __builtin_amdgcn_mfma_f32_16x16x32_bf16(a, bk_, S[j], 0, 0, 0);
            }
        }

        // online softmax (C layout: row = quad*4+r, col = j*16+l16)
        float alpha[4];
        #pragma unroll
        for (int r = 0; r < 4; r++){
            float mx = fmaxf(fmaxf(S[0][r], S[1][r]), fmaxf(S[2][r], S[3][r]));
            #pragma unroll
            for (int o = 1; o < 16; o <<= 1) mx = fmaxf(mx, __shfl_xor(mx, o, 64));
            float mn = fmaxf(m_[r], mx);
            alpha[r] = __expf(m_[r] - mn);
            m_[r] = mn;
            float rs = 0.f;
            #pragma unroll
            for (int j = 0; j < 4; j++){
                float p = __expf(S[j][r] - mn);
                S[j][r] = p;
                rs += p;
            }
            #pragma unroll
            for (int o = 1; o < 16; o <<= 1) rs += __shfl_xor(rs, o, 64);
            l_[r] = l_[r] * alpha[r] + rs;
        }

        // P -> bf16 -> per-wave LDS (C layout write)
        #pragma unroll
        for (int j = 0; j < 4; j++)
            #pragma unroll
            for (int r = 0; r < 4; r++)
                Ps[wave][quad*4 + r][j*16 + l16] = f2bf(S[j][r]);

        // rescale O
        #pragma unroll
        for (int j = 0; j < 4; j++)
            #pragma unroll
            for (int r = 0; r < 4; r++)
                O[j][r] *= alpha[r];

        // O += P @ V   (A = P from LDS in A-layout, B = Vt)
        #pragma unroll
        for (int st = 0; st < 2; st++){
            bf16x8 a = *(const bf16x8*)&Ps[wave][l16][quad*8 + st*32];
            #pragma unroll
            for (int j = 0; j < 4; j++){
                bf16x8 bv = *(const bf16x8*)&Vt[j*16 + l16][quad*8 + st*32];
                O[j] = __builtin_amdgcn_mfma_f32_16x16x32_bf16(a, bv, O[j], 0, 0, 0);
            }
        }
    }

    // epilogue: O / l -> bf16 out
    #pragma unroll
    for (int r = 0; r < 4; r++){
        float inv = 1.0f / l_[r];
        long row = rowbase + q0 + wm + quad*4 + r;
        short* op = (short*)Ob + row*768 + hoff;
        #pragma unroll
        for (int j = 0; j < 4; j++)
            op[j*16 + l16] = f2bf(O[j][r] * inv);
    }
}

// ---------- final projection 768 -> 5 ----------
__global__ void outproj_k(const float* __restrict__ h, const float* __restrict__ W,
                          const float* __restrict__ b, float* __restrict__ out)
{
    int idx = blockIdx.x*256 + threadIdx.x;
    if (idx >= NN*5) return;
    int n = idx / 5, o = idx % 5;
    float acc = b[o];
    for (int k = 0; k < HID; k++) acc += h[(long)n*HID + k] * W[k*5 + o];
    out[idx] = acc;
}

// ---------- host launch ----------
extern "C" void kernel_launch(void* const* d_in, const int* in_sizes, int n_in,
                              void* d_out, int out_size, void* d_ws, size_t ws_size,
                              hipStream_t stream)
{
    const float* text_x = (const float*)d_in[0];
    const float* img_x  = (const float*)d_in[1];
    const int*   bbox   = (const int*)d_in[2];
    const int*   ei[3]  = {(const int*)d_in[3], (const int*)d_in[4], (const int*)d_in[5]};
    const float* ea[3]  = {(const float*)d_in[6], (const float*)d_in[7], (const float*)d_in[8]};
    const float* Wt = (const float*)d_in[9];   const float* bt = (const float*)d_in[10];
    const float* Wi = (const float*)d_in[11];  const float* bi = (const float*)d_in[12];
    const float* Ex = (const float*)d_in[13];  const float* Ey = (const float*)d_in[14];
    const float* Wc = (const float*)d_in[15];  const float* bc = (const float*)d_in[16];
    const float* gat_W  = (const float*)d_in[17];
    const float* gat_as = (const float*)d_in[18];
    const float* gat_ad = (const float*)d_in[19];
    const float* gat_We = (const float*)d_in[20];
    const float* gat_ae = (const float*)d_in[21];
    const float* gat_bias = (const float*)d_in[22];
    const float* ln_g = (const float*)d_in[23]; const float* ln_b = (const float*)d_in[24];
    const float* Wcomb = (const float*)d_in[25]; const float* bcomb = (const float*)d_in[26];
    const float* pos_emb = (const float*)d_in[27]; const float* type_emb = (const float*)d_in[28];
    const float* emb_g = (const float*)d_in[29]; const float* emb_b = (const float*)d_in[30];
    const float* Wq = (const float*)d_in[31]; const float* Wk = (const float*)d_in[32];
    const float* Wv = (const float*)d_in[33]; const float* Wo = (const float*)d_in[34];
    const float* W1 = (const float*)d_in[35]; const float* W2 = (const float*)d_in[36];
    const float* bq = (const float*)d_in[37]; const float* bk = (const float*)d_in[38];
    const float* bv = (const float*)d_in[39]; const float* bo = (const float*)d_in[40];
    const float* bff1 = (const float*)d_in[41]; const float* bff2 = (const float*)d_in[42];
    const float* ln1_g = (const float*)d_in[43]; const float* ln1_b = (const float*)d_in[44];
    const float* ln2_g = (const float*)d_in[45]; const float* ln2_b = (const float*)d_in[46];
    const float* Wout = (const float*)d_in[47]; const float* bout = (const float*)d_in[48];
    float* outp = (float*)d_out;

    // ---- workspace carve ----
    char* p0 = (char*)d_ws; char* p = p0;
    auto carve = [&](size_t b)->char*{ char* r = p; p += (b + 255) & ~(size_t)255; return r; };

    __hip_bfloat16* gatWT  = (__hip_bfloat16*)carve(6L*768*768*2);
    __hip_bfloat16* WcT    = (__hip_bfloat16*)carve(768L*768*2);
    __hip_bfloat16* WcombT = (__hip_bfloat16*)carve(768L*1536*2);
    __hip_bfloat16* WtT    = (__hip_bfloat16*)carve(256L*768*2);
    __hip_bfloat16* WiT    = (__hip_bfloat16*)carve(256L*512*2);
    float* qbias           = (float*)carve(12L*2304*4);
    __hip_bfloat16* featb  = (__hip_bfloat16*)carve(4096L*1536*2);
    float* hb              = (float*)carve(4096L*768*4);
    __hip_bfloat16* hbb    = (__hip_bfloat16*)carve(4096L*768*2);
    char* U                = carve(56623104);   // union region
    float* asrc = (float*)carve(4096L*8*4);
    float* adst = (float*)carve(4096L*8*4);
    float* sumea= (float*)carve(3L*4096*4);
    int* cnt    = (int*)carve(3L*4096*4);
    int* offs   = (int*)carve(3L*4097*4);
    int* posb   = (int*)carve(4096L*4);
    int* eid    = (int*)carve(3L*65536*4);

    size_t used = (size_t)(p - p0);
    size_t bert_all = 42467328UL + 14155776UL + 56623104UL + 56623104UL + 2048UL;
    bool big = (ws_size > used) && ((ws_size - used) >= bert_all);
    __hip_bfloat16* WqkvT = (__hip_bfloat16*)carve(big ? 12L*2304*768*2 : 2304L*768*2);
    __hip_bfloat16* WoT   = (__hip_bfloat16*)carve(big ? 12L*768*768*2  : 768L*768*2);
    __hip_bfloat16* W1T   = (__hip_bfloat16*)carve(big ? 12L*3072*768*2 : 3072L*768*2);
    __hip_bfloat16* W2T   = (__hip_bfloat16*)carve(big ? 12L*768*3072*2 : 768L*3072*2);
    long sQ = big ? 2304L*768 : 0, sO = big ? 768L*768 : 0;
    long s1 = big ? 3072L*768 : 0, s2 = big ? 768L*3072 : 0;

    // U overlays:
    // GAT phase: xb_bf[0,6.3M) outg[6.3M,18.9M) hbuf[18.9M,56.6M)
    // BERT phase: qkvb bf16 [0,18.9M) -> attn -> ctxb [37.75M,44.05M);
    //             tmp f32 [0,12.6M) (Wo/FF2 out, overwrites dead qkvb);
    //             ffb bf16 [12.6M,37.75M) (overwrites dead qkvb tail)
    __hip_bfloat16* xb_bf   = (__hip_bfloat16*)U;
    float*          outg    = (float*)(U + 6291456);
    float*          hbuf    = (float*)(U + 18874368);
    __hip_bfloat16* text_bf = (__hip_bfloat16*)(U + 12582912);
    __hip_bfloat16* img_bf  = (__hip_bfloat16*)(U + 18874368);
    float*          tmp     = (float*)U;
    __hip_bfloat16* ffb     = (__hip_bfloat16*)(U + 12582912);
    __hip_bfloat16* qkvb    = (__hip_bfloat16*)U;
    __hip_bfloat16* ctxb    = (__hip_bfloat16*)(U + 37748736);

    // ---- 0. weight conversions ----
    cvt_k<<<3072, 256, 0, stream>>>(text_x, text_bf, NN*768);
    cvt_k<<<2048, 256, 0, stream>>>(img_x,  img_bf,  NN*512);
    tconv_k<<<dim3(8,24,1),  256, 0, stream>>>(Wt, WtT, 768, 192, 0, 0);
    tconv_k<<<dim3(8,16,1),  256, 0, stream>>>(Wi, WiT, 512, 192, 0, 0);
    tconv_k<<<dim3(24,24,1), 256, 0, stream>>>(Wc, WcT, 768, 768, 0, 0);
    tconv_k<<<dim3(24,48,1), 256, 0, stream>>>(Wcomb, WcombT, 1536, 768, 0, 0);
    tconv_k<<<dim3(24,24,6), 256, 0, stream>>>(gat_W, gatWT, 768, 768, 589824, 589824);
    packb_k<<<108, 256, 0, stream>>>(bq, bk, bv, qbias);
    if (big){
        tconv_k<<<dim3(24,24,12), 256, 0, stream>>>(Wq, WqkvT,           768, 768, 589824, 1769472);
        tconv_k<<<dim3(24,24,12), 256, 0, stream>>>(Wk, WqkvT + 589824,  768, 768, 589824, 1769472);
        tconv_k<<<dim3(24,24,12), 256, 0, stream>>>(Wv, WqkvT + 1179648, 768, 768, 589824, 1769472);
        tconv_k<<<dim3(24,24,12), 256, 0, stream>>>(Wo, WoT, 768, 768,  589824, 589824);
        tconv_k<<<dim3(96,24,12), 256, 0, stream>>>(W1, W1T, 768, 3072, 2359296, 2359296);
        tconv_k<<<dim3(24,96,12), 256, 0, stream>>>(W2, W2T, 3072, 768, 2359296, 2359296);
    }

    // ---- 1. input projections ----
    bgemm_k<0,0,1><<<dim3(2,32), 256, 0, stream>>>(text_bf, WtT, bt, nullptr, featb,     192, 768, 768, 768, 0, 1536);
    bgemm_k<0,0,1><<<dim3(2,32), 256, 0, stream>>>(img_bf,  WiT, bi, nullptr, featb+192, 192, 512, 512, 512, 0, 1536);
    spat_k<<<6144, 256, 0, stream>>>(bbox, Ex, Ey, featb);
    bgemm_k<1,0,1><<<dim3(6,32), 256, 0, stream>>>(featb, WcT, bc, nullptr, xb_bf, 768, 768, 1536, 768, 0, 768);

    // ---- 2. CSR per edge type ----
    zero_i<<<48, 256, 0, stream>>>(cnt, 3*NN);
    zero_f<<<48, 256, 0, stream>>>(sumea, 3*NN);
    for (int t = 0; t < 3; t++){
        count_k<<<EE/256, 256, 0, stream>>>(ei[t] + EE, ea[t], cnt + t*NN, sumea + t*NN);
        scan_k<<<1, 256, 0, stream>>>(cnt + t*NN, offs + t*(NN+1));
        loopea_k<<<NN/256, 256, 0, stream>>>(cnt + t*NN, sumea + t*NN);
        copy_i<<<NN/256, 256, 0, stream>>>(offs + t*(NN+1), posb, NN);
        fill_k<<<EE/256, 256, 0, stream>>>(ei[t] + EE, posb, eid + t*EE);
    }

    // ---- 3. GAT layers ----
    for (int l = 0; l < 2; l++){
        zero_f<<<12288, 256, 0, stream>>>(outg, NN*HID);
        bgemm_k<0,1,0><<<dim3(18,32), 256, 0, stream>>>(xb_bf, gatWT + (long)l*1769472, nullptr,
                                                        hbuf, nullptr, 2304, 768, 768, 768, 2304, 0);
        for (int t = 0; t < 3; t++){
            int lt = l*3 + t;
            headprep_k<<<NN, 64, 0, stream>>>(hbuf + t*768, 2304, gat_as + lt*768, gat_ad + lt*768, asrc, adst);
            gatagg_k<<<NN, 256, 0, stream>>>(hbuf + t*768, 2304, asrc, adst, ei[t], ea[t], sumea + t*NN,
                                             offs + t*(NN+1), eid + t*EE,
                                             gat_We + lt*768, gat_ae + lt*768,
                                             gat_bias + lt*768, outg);
        }
        if (l == 0)
            ln_k<<<NN, 256, 0, stream>>>(outg, nullptr, nullptr, nullptr, ln_g, ln_b,
                                         nullptr, 0, xb_bf, 768, 1e-5f, 1);
        else
            ln_k<<<NN, 256, 0, stream>>>(outg, nullptr, nullptr, nullptr, ln_g + HID, ln_b + HID,
                                         nullptr, 0, featb + 768, 1536, 1e-5f, 1);
    }

    // ---- 4. comb + embedding LN ----
    bgemm_k<1,1,0><<<dim3(6,32), 256, 0, stream>>>(featb, WcombT, bcomb, tmp, nullptr,
                                                   768, 1536, 1536, 1536, 768, 0);
    ln_k<<<NN, 256, 0, stream>>>(tmp, nullptr, pos_emb, type_emb, emb_g, emb_b, hb, 768, hbb, 768, 1e-12f, 0);

    // ---- 5. BERT layers ----
    for (int l = 0; l < 12; l++){
        if (!big){
            tconv_k<<<dim3(24,24,1), 256, 0, stream>>>(Wq + (long)l*589824, WqkvT,           768, 768, 0, 0);
            tconv_k<<<dim3(24,24,1), 256, 0, stream>>>(Wk + (long)l*589824, WqkvT + 589824,  768, 768, 0, 0);
            tconv_k<<<dim3(24,24,1), 256, 0, stream>>>(Wv + (long)l*589824, WqkvT + 1179648, 768, 768, 0, 0);
            tconv_k<<<dim3(24,24,1), 256, 0, stream>>>(Wo + (long)l*589824, WoT, 768, 768, 0, 0);
            tconv_k<<<dim3(96,24,1), 256, 0, stream>>>(W1 + (long)l*2359296, W1T, 768, 3072, 0, 0);
            tconv_k<<<dim3(24,96,1), 256, 0, stream>>>(W2 + (long)l*2359296, W2T, 3072, 768, 0, 0);
        }
        const __hip_bfloat16* wq = WqkvT + l*sQ;
        const __hip_bfloat16* wo = WoT + l*sO;
        const __hip_bfloat16* w1 = W1T + l*s1;
        const __hip_bfloat16* w2 = W2T + l*s2;
        bgemm_k<0,0,1><<<dim3(18,32), 256, 0, stream>>>(hbb, wq, qbias + l*2304, nullptr, qkvb,
                                                        2304, 768, 768, 768, 0, 2304);
        attn2_k<<<dim3(8,12,8), 256, 0, stream>>>(qkvb, ctxb);
        bgemm_k<0,1,0><<<dim3(6,32), 256, 0, stream>>>(ctxb, wo, bo + l*768, tmp, nullptr,
                                                       768, 768, 768, 768, 768, 0);
        ln_k<<<NN, 256, 0, stream>>>(hb, tmp, nullptr, nullptr, ln1_g + l*768, ln1_b + l*768,
                                     hb, 768, hbb, 768, 1e-12f, 0);
        bgemm_k<2,0,1><<<dim3(24,32), 256, 0, stream>>>(hbb, w1, bff1 + l*3072, nullptr, ffb,
                                                        3072, 768, 768, 768, 0, 3072);
        bgemm_k<0,1,0><<<dim3(6,32), 256, 0, stream>>>(ffb, w2, bff2 + l*768, tmp, nullptr,
                                                       768, 3072, 3072, 3072, 768, 0);
        ln_k<<<NN, 256, 0, stream>>>(hb, tmp, nullptr, nullptr, ln2_g + l*768, ln2_b + l*768,
                                     hb, 768, hbb, 768, 1e-12f, 0);
    }

    // ---- 6. output head ----
    outproj_k<<<80, 256, 0, stream>>>(hb, Wout, bout, outp);
}